// Round 7
// baseline (165.601 us; speedup 1.0000x reference)
//
#include <hip/hip_runtime.h>
#include <math.h>

#define BS 2048   // B*S tokens
#define H  1024
#define E  8
#define F  512

typedef __attribute__((ext_vector_type(8))) short bf16x8;
typedef __attribute__((ext_vector_type(4))) float f32x4;
typedef unsigned short u16;
typedef unsigned int u32;

__device__ inline u16 f2bf(float f) {
    u32 u = __float_as_uint(f);
    return (u16)((u + 0x7fffu + ((u >> 16) & 1u)) >> 16);
}

// async 16B global->LDS. LDS dst is wave-uniform base + lane*16 by construction.
__device__ __forceinline__ void async_cp16(const u16* g, u16* l) {
    __builtin_amdgcn_global_load_lds(
        (const __attribute__((address_space(1))) void*)g,
        (__attribute__((address_space(3))) void*)l, 16, 0, 0);
}

// ws layout (bytes):
//        0: counters: [16..24) = per-expert gathered counts
//     4096: sel      int2[BS]   (expert id | valid<<8 | mismatch<<9 per slot)
//    20480: wsel     float2[BS]
//    36864: tok_list int[E*BS]
//   102400: w_list   float[E*BS]
//   167936: x_bf     u16[BS*H]            (4 MB)
//  4362240: gup_t    u16[E*1024*1024]     (16 MB)  [e][f-col][h-k] transposed bf16
// 21139456: down_t   u16[E*1024*512]      (8 MB)   [e][h-col][f-k] transposed bf16
// 29528064: act      u16[4096*F]          (4 MB)   w-scaled silu(g)*u, bf16

// ---- K1: fused gup transpose (blocks 0..2047) + router (blocks 2048..2559) ----
__global__ __launch_bounds__(256) void prep_router_kernel(
    const float* __restrict__ gup, u16* __restrict__ gt,
    const float* __restrict__ x, const float* __restrict__ gate_w,
    const int* __restrict__ tok_mod, const int* __restrict__ exp_mod,
    int2* __restrict__ sel_out, float2* __restrict__ w_out,
    u16* __restrict__ xb, float* __restrict__ out)
{
    int b = blockIdx.x;
    int tid = threadIdx.x;

    if (b < 2048) {
        // gup transpose: fp32 [k=h][n=f2] -> bf16 [n][k]
        int e = b >> 8; int rem = b & 255; int kt = rem >> 4, nt = rem & 15;
        const float* src = gup + (size_t)e * 1048576;
        u16* dst_base = gt + (size_t)e * 1048576;
        int k0 = kt * 64, n0 = nt * 64;
        __shared__ float t[64][68];
        int r = tid >> 2, c4 = tid & 3;
        const float* srow = src + (size_t)(k0 + r) * 1024 + n0 + c4 * 16;
#pragma unroll
        for (int i = 0; i < 4; i++) {
            float4 v = *(const float4*)(srow + i * 4);
            *(float4*)&t[r][c4 * 16 + i * 4] = v;
        }
        __syncthreads();
        u16 o[16];
#pragma unroll
        for (int m = 0; m < 16; m++) o[m] = f2bf(t[c4 * 16 + m][r]);
        u16* dst = dst_base + (size_t)(n0 + r) * 1024 + k0 + c4 * 16;
        uint4 q0, q1;
        q0.x = (u32)o[0] | ((u32)o[1] << 16);  q0.y = (u32)o[2] | ((u32)o[3] << 16);
        q0.z = (u32)o[4] | ((u32)o[5] << 16);  q0.w = (u32)o[6] | ((u32)o[7] << 16);
        q1.x = (u32)o[8] | ((u32)o[9] << 16);  q1.y = (u32)o[10] | ((u32)o[11] << 16);
        q1.z = (u32)o[12] | ((u32)o[13] << 16); q1.w = (u32)o[14] | ((u32)o[15] << 16);
        *(uint4*)dst = q0;
        *(uint4*)(dst + 8) = q1;
        return;
    }

    // router: one wave per token, 4 tokens per block
    int wv = tid >> 6, lane = tid & 63;
    int token = (b - 2048) * 4 + wv;
    float4 z = make_float4(0.f, 0.f, 0.f, 0.f);
    float4* orow4 = (float4*)(out + (size_t)token * H);
#pragma unroll
    for (int i = 0; i < 4; i++) orow4[lane + 64 * i] = z;

    const float4* xr4 = (const float4*)(x + (size_t)token * H);
    const float4* gw4 = (const float4*)gate_w;
    float acc[E];
#pragma unroll
    for (int e = 0; e < E; e++) acc[e] = 0.f;
#pragma unroll
    for (int i = 0; i < 4; i++) {
        int idx = lane + 64 * i;
        float4 xv = xr4[idx];
        ushort4 pk;
        pk.x = f2bf(xv.x); pk.y = f2bf(xv.y); pk.z = f2bf(xv.z); pk.w = f2bf(xv.w);
        *(ushort4*)(xb + (size_t)token * H + idx * 4) = pk;
#pragma unroll
        for (int e = 0; e < E; e++) {
            float4 g = gw4[e * 256 + idx];
            acc[e] += xv.x * g.x + xv.y * g.y + xv.z * g.z + xv.w * g.w;
        }
    }
#pragma unroll
    for (int e = 0; e < E; e++) {
#pragma unroll
        for (int off = 32; off > 0; off >>= 1) acc[e] += __shfl_down(acc[e], off, 64);
    }
    if (lane == 0) {
        float m = acc[0];
#pragma unroll
        for (int e = 1; e < E; e++) m = fmaxf(m, acc[e]);
        float p[E]; float s = 0.f;
#pragma unroll
        for (int e = 0; e < E; e++) { p[e] = expf(acc[e] - m); s += p[e]; }
        float inv = 1.f / s;
#pragma unroll
        for (int e = 0; e < E; e++) p[e] *= inv;
        int i0 = 0; float p0 = p[0];
#pragma unroll
        for (int e = 1; e < E; e++) if (p[e] > p0) { p0 = p[e]; i0 = e; }
        int i1 = -1; float p1 = -1.f;
#pragma unroll
        for (int e = 0; e < E; e++) if (e != i0 && p[e] > p1) { p1 = p[e]; i1 = e; }
        float rs = 1.f / (p0 + p1);
        float w0 = p0 * rs, w1 = p1 * rs;
        int tm = tok_mod[token];
        int em0 = exp_mod[i0], em1 = exp_mod[i1];
        int v0 = (tm != 0) && (em0 != 0);
        int v1 = (tm != 0) && (em1 != 0);
        int mm0 = v0 && (tm * em0 == -1);
        int mm1 = v1 && (tm * em1 == -1);
        sel_out[token] = make_int2(i0 | (v0 << 8) | (mm0 << 9),
                                   i1 | (v1 << 8) | (mm1 << 9));
        w_out[token] = make_float2(w0, w1);
    }
}

// ---- K2: single-block finalize: reduce valid/mismatch, skip, renorm, gather ----
__global__ __launch_bounds__(1024) void finalize_kernel(
    const int* __restrict__ exp_mod, int* __restrict__ counters,
    const int2* __restrict__ sel_in, const float2* __restrict__ w_in,
    int* __restrict__ tok_list, float* __restrict__ w_list)
{
    __shared__ int vcnt[E], mcnt[E], gpos[E];
    int tid = threadIdx.x;
    if (tid < E) { vcnt[tid] = 0; mcnt[tid] = 0; gpos[tid] = 0; }
    __syncthreads();
#pragma unroll
    for (int h = 0; h < 2; h++) {
        int t = tid + h * 1024;
        int2 s = sel_in[t];
        int i0 = s.x & 7, i1 = s.y & 7;
        if (s.x & 256) atomicAdd(&vcnt[i0], 1);
        if (s.x & 512) atomicAdd(&mcnt[i0], 1);
        if (s.y & 256) atomicAdd(&vcnt[i1], 1);
        if (s.y & 512) atomicAdd(&mcnt[i1], 1);
    }
    __syncthreads();
    bool skip[E];
#pragma unroll
    for (int e = 0; e < E; e++)
        skip[e] = (vcnt[e] > 0) && (mcnt[e] == vcnt[e]) && (exp_mod[e] != 0);
#pragma unroll
    for (int h = 0; h < 2; h++) {
        int t = tid + h * 1024;
        int2 s = sel_in[t];
        int i0 = s.x & 7, i1 = s.y & 7;
        float2 w = w_in[t];
        float w0 = skip[i0] ? 0.f : w.x;
        float w1 = skip[i1] ? 0.f : w.y;
        float sm = w0 + w1;
        if (sm > 0.f) { float inv = 1.f / fmaxf(sm, 1e-9f); w0 *= inv; w1 *= inv; }
        if (w0 > 0.f) {
            int pos = atomicAdd(&gpos[i0], 1);
            tok_list[i0 * BS + pos] = t; w_list[i0 * BS + pos] = w0;
        }
        if (w1 > 0.f) {
            int pos = atomicAdd(&gpos[i1], 1);
            tok_list[i1 * BS + pos] = t; w_list[i1 * BS + pos] = w1;
        }
    }
    __syncthreads();
    if (tid < E) counters[16 + tid] = gpos[tid];
}

// ---- K3: gu MFMA tile M=32 N=128 (g64|u64), BK=64, dbuf, XOR swizzle.
//      blockIdx.y >= 64: helper blocks transposing down-weights (overlap).
__global__ __launch_bounds__(256) void gu_mfma_kernel(
    const u16* __restrict__ xb, const u16* __restrict__ gup_t,
    const int* __restrict__ counters, const int* __restrict__ tok_list,
    const float* __restrict__ w_list, u16* __restrict__ act,
    const float* __restrict__ dwn, u16* __restrict__ dt)
{
    __shared__ __align__(16) char smem[40960];
    int tid = threadIdx.x;

    if (blockIdx.y >= 64) {
        // ---- helper: down transpose, 4 tiles per block ----
        float (*t)[68] = (float(*)[68])smem;
        int hb = blockIdx.x + 8 * (blockIdx.y - 64) + 32 * blockIdx.z;   // [0,256)
        int r = tid >> 2, c4 = tid & 3;
#pragma unroll
        for (int i = 0; i < 4; i++) {
            int tile = hb * 4 + i;                 // [0,1024)
            int e = tile >> 7; int rem = tile & 127;
            int k0 = (rem >> 4) * 64, n0 = (rem & 15) * 64;
            const float* srow = dwn + (size_t)e * 524288 + (size_t)(k0 + r) * 1024 + n0 + c4 * 16;
#pragma unroll
            for (int q = 0; q < 4; q++) {
                float4 v = *(const float4*)(srow + q * 4);
                *(float4*)&t[r][c4 * 16 + q * 4] = v;
            }
            __syncthreads();
            u16 o[16];
#pragma unroll
            for (int m = 0; m < 16; m++) o[m] = f2bf(t[c4 * 16 + m][r]);
            u16* dst = dt + (size_t)e * 524288 + (size_t)(n0 + r) * 512 + k0 + c4 * 16;
            uint4 q0, q1;
            q0.x = (u32)o[0] | ((u32)o[1] << 16);  q0.y = (u32)o[2] | ((u32)o[3] << 16);
            q0.z = (u32)o[4] | ((u32)o[5] << 16);  q0.w = (u32)o[6] | ((u32)o[7] << 16);
            q1.x = (u32)o[8] | ((u32)o[9] << 16);  q1.y = (u32)o[10] | ((u32)o[11] << 16);
            q1.z = (u32)o[12] | ((u32)o[13] << 16); q1.w = (u32)o[14] | ((u32)o[15] << 16);
            *(uint4*)dst = q0;
            *(uint4*)(dst + 8) = q1;
            __syncthreads();
        }
        return;
    }

    // ---- gu GEMM ----
    int e = blockIdx.z;
    int n = counters[16 + e];
    int t0 = blockIdx.y * 32;
    if (t0 >= n) return;
    int f0 = blockIdx.x * 64;
    int base = 0;
#pragma unroll
    for (int i = 0; i < E; i++) if (i < e) base += counters[16 + i];

    u16 (*Asl)[32 * 64] = (u16(*)[32 * 64])smem;            // 2 x 4 KB
    u16 (*Bsl)[128 * 64] = (u16(*)[128 * 64])(smem + 8192); // 2 x 16 KB

    int wv = tid >> 6, lane = tid & 63;
    int l16 = lane & 15, quad = lane >> 4;

    int lr = lane >> 3, lc = lane & 7;
    // A staging: rows 0..31, one issue; row = wv*8 + lr
    int r0 = wv * 8 + lr;
    int tokA = tok_list[e * BS + min(t0 + r0, n - 1)];
    const u16* agp = xb + (size_t)tokA * H + (size_t)((lc ^ (r0 & 7)) * 8);
    int alo = r0 * 64 + lc * 8;
    // B staging: 4 issues, cols j*32 + wv*8 + lr
    const u16* gb = gup_t + ((size_t)e << 20);
    const u16* bgp[4]; int blo[4];
#pragma unroll
    for (int j = 0; j < 4; j++) {
        int c = j * 32 + wv * 8 + lr;
        int gcol = (c < 64) ? (f0 + c) : (512 + f0 + (c - 64));
        bgp[j] = gb + (size_t)gcol * H + (size_t)((lc ^ (c & 7)) * 8);
        blo[j] = c * 64 + lc * 8;
    }

    f32x4 acc[2][2];   // [m-frag][g/u]
#pragma unroll
    for (int i = 0; i < 2; i++)
#pragma unroll
        for (int j = 0; j < 2; j++) acc[i][j] = (f32x4){0.f, 0.f, 0.f, 0.f};

    async_cp16(agp, &Asl[0][alo]);
#pragma unroll
    for (int j = 0; j < 4; j++) async_cp16(bgp[j], &Bsl[0][blo[j]]);

    int sw = l16 & 7;
    int p = 0;
    for (int k0 = 0; k0 < H; k0 += 64) {
        __syncthreads();
        if (k0 + 64 < H) {
            int q = p ^ 1;
            async_cp16(agp + k0 + 64, &Asl[q][alo]);
#pragma unroll
            for (int j = 0; j < 4; j++) async_cp16(bgp[j] + k0 + 64, &Bsl[q][blo[j]]);
        }
#pragma unroll
        for (int s = 0; s < 2; s++) {
            int ch = ((s * 4 + quad) ^ sw) * 8;
            bf16x8 af[2];
#pragma unroll
            for (int i = 0; i < 2; i++)
                af[i] = *(const bf16x8*)&Asl[p][(i * 16 + l16) * 64 + ch];
            bf16x8 bg = *(const bf16x8*)&Bsl[p][(wv * 16 + l16) * 64 + ch];
            bf16x8 bu = *(const bf16x8*)&Bsl[p][(64 + wv * 16 + l16) * 64 + ch];
#pragma unroll
            for (int i = 0; i < 2; i++) {
                acc[i][0] = __builtin_amdgcn_mfma_f32_16x16x32_bf16(af[i], bg, acc[i][0], 0, 0, 0);
                acc[i][1] = __builtin_amdgcn_mfma_f32_16x16x32_bf16(af[i], bu, acc[i][1], 0, 0, 0);
            }
        }
        p ^= 1;
    }
    // epilogue: C layout col=l16, row=quad*4+reg; wave wv owns 16 g/u col pair
#pragma unroll
    for (int i = 0; i < 2; i++)
#pragma unroll
        for (int r = 0; r < 4; r++) {
            int R = t0 + i * 16 + quad * 4 + r;
            if (R < n) {
                float w = w_list[e * BS + R];
                float g = acc[i][0][r], u = acc[i][1][r];
                float v = (g / (1.f + expf(-g))) * u * w;
                act[(size_t)(base + R) * F + f0 + wv * 16 + l16] = f2bf(v);
            }
        }
}

// ---- K4: down MFMA tile M=32, N=128 h-cols, K=F=512, dbuf, atomic scatter ----
__global__ __launch_bounds__(256) void down_mfma_kernel(
    const u16* __restrict__ act, const u16* __restrict__ down_t,
    const int* __restrict__ counters, const int* __restrict__ tok_list,
    float* __restrict__ out)
{
    int e = blockIdx.z;
    int n = counters[16 + e];
    int t0 = blockIdx.y * 32;
    if (t0 >= n) return;
    int h0 = blockIdx.x * 128;
    int base = 0;
#pragma unroll
    for (int i = 0; i < E; i++) if (i < e) base += counters[16 + i];

    __shared__ __align__(16) u16 Asl[2][32 * 64];    // 2 x 4 KB
    __shared__ __align__(16) u16 Bsl[2][128 * 64];   // 2 x 16 KB

    int tid = threadIdx.x;
    int wv = tid >> 6, lane = tid & 63;
    int l16 = lane & 15, quad = lane >> 4;

    int lr = lane >> 3, lc = lane & 7;
    int r0 = wv * 8 + lr;
    const u16* agp = act + (size_t)(base + min(t0 + r0, n - 1)) * F + (size_t)((lc ^ (r0 & 7)) * 8);
    int alo = r0 * 64 + lc * 8;
    const u16* db = down_t + ((size_t)e << 19);
    const u16* bgp[4]; int blo[4];
#pragma unroll
    for (int j = 0; j < 4; j++) {
        int c = j * 32 + wv * 8 + lr;
        bgp[j] = db + (size_t)(h0 + c) * F + (size_t)((lc ^ (c & 7)) * 8);
        blo[j] = c * 64 + lc * 8;
    }

    f32x4 acc[2][2];   // [m-frag][n-frag]; wave wv owns cols wv*32..wv*32+32
#pragma unroll
    for (int i = 0; i < 2; i++)
#pragma unroll
        for (int j = 0; j < 2; j++) acc[i][j] = (f32x4){0.f, 0.f, 0.f, 0.f};

    async_cp16(agp, &Asl[0][alo]);
#pragma unroll
    for (int j = 0; j < 4; j++) async_cp16(bgp[j], &Bsl[0][blo[j]]);

    int sw = l16 & 7;
    int p = 0;
    for (int k0 = 0; k0 < F; k0 += 64) {
        __syncthreads();
        if (k0 + 64 < F) {
            int q = p ^ 1;
            async_cp16(agp + k0 + 64, &Asl[q][alo]);
#pragma unroll
            for (int j = 0; j < 4; j++) async_cp16(bgp[j] + k0 + 64, &Bsl[q][blo[j]]);
        }
#pragma unroll
        for (int s = 0; s < 2; s++) {
            int ch = ((s * 4 + quad) ^ sw) * 8;
            bf16x8 af[2], b0, b1;
#pragma unroll
            for (int i = 0; i < 2; i++)
                af[i] = *(const bf16x8*)&Asl[p][(i * 16 + l16) * 64 + ch];
            b0 = *(const bf16x8*)&Bsl[p][(wv * 32 + l16) * 64 + ch];
            b1 = *(const bf16x8*)&Bsl[p][(wv * 32 + 16 + l16) * 64 + ch];
#pragma unroll
            for (int i = 0; i < 2; i++) {
                acc[i][0] = __builtin_amdgcn_mfma_f32_16x16x32_bf16(af[i], b0, acc[i][0], 0, 0, 0);
                acc[i][1] = __builtin_amdgcn_mfma_f32_16x16x32_bf16(af[i], b1, acc[i][1], 0, 0, 0);
            }
        }
        p ^= 1;
    }
#pragma unroll
    for (int i = 0; i < 2; i++)
#pragma unroll
        for (int r = 0; r < 4; r++) {
            int R = t0 + i * 16 + quad * 4 + r;
            if (R < n) {
                int tok = tok_list[e * BS + R];
                float* orow = out + (size_t)tok * H + h0 + wv * 32 + l16;
                atomicAdd(&orow[0],  acc[i][0][r]);
                atomicAdd(&orow[16], acc[i][1][r]);
            }
        }
}

extern "C" void kernel_launch(void* const* d_in, const int* in_sizes, int n_in,
                              void* d_out, int out_size, void* d_ws, size_t ws_size,
                              hipStream_t stream)
{
    const float* x       = (const float*)d_in[0];
    const float* gate_w  = (const float*)d_in[1];
    const float* gup     = (const float*)d_in[2];
    const float* down    = (const float*)d_in[3];
    const int*   tok_mod = (const int*)d_in[4];
    const int*   exp_mod = (const int*)d_in[5];
    float* out = (float*)d_out;

    char* ws = (char*)d_ws;
    int*    counters = (int*)ws;
    int2*   sel      = (int2*)(ws + 4096);
    float2* wsel     = (float2*)(ws + 20480);
    int*    tok_list = (int*)(ws + 36864);
    float*  w_list   = (float*)(ws + 102400);
    u16*    x_bf     = (u16*)(ws + 167936);
    u16*    gup_t    = (u16*)(ws + 4362240);
    u16*    down_t   = (u16*)(ws + 21139456);
    u16*    act      = (u16*)(ws + 29528064);

    prep_router_kernel<<<2560, 256, 0, stream>>>(gup, gup_t, x, gate_w, tok_mod, exp_mod,
                                                 sel, wsel, x_bf, out);
    finalize_kernel<<<1, 1024, 0, stream>>>(exp_mod, counters, sel, wsel, tok_list, w_list);
    gu_mfma_kernel<<<dim3(8, 68, E), 256, 0, stream>>>(x_bf, gup_t, counters, tok_list, w_list, act,
                                                       down, down_t);
    down_mfma_kernel<<<dim3(8, 64, E), 256, 0, stream>>>(act, down_t, counters, tok_list, out);
}